// Round 9
// baseline (2618.064 us; speedup 1.0000x reference)
//
#include <hip/hip_runtime.h>
#include <cmath>

typedef __bf16 bf16x8 __attribute__((ext_vector_type(8)));
typedef float  f32x4  __attribute__((ext_vector_type(4)));

template <int N> struct IC { static constexpr int v = N; };

// GEMM: BM=256 (=M), BN=128, BK=64, 512 threads (8 waves).
#define ATILE 32768        // A tile: 256 rows * 128B (bf16, swizzled)
#define WTILE 16384        // W tile: 128 rows * 128B (bf16, swizzled)
#define LDS_W_OFF 65536    // after 2 A buffers
// LDS total: 2*32KB + 2*16KB = 96KB -> 1 block/CU

#define GLOAD_LDS16(g, l)                                                    \
    __builtin_amdgcn_global_load_lds(                                        \
        (const __attribute__((address_space(1))) unsigned int*)(g),          \
        (__attribute__((address_space(3))) unsigned int*)(l), 16, 0, 0)

#define SBAR()  __builtin_amdgcn_s_barrier()
#define SCHED() __builtin_amdgcn_sched_barrier(0)

__device__ __forceinline__ int swz(int row, int byteInRow) {
    return row * 128 + (byteInRow ^ ((row & 7) << 4));
}

__device__ __forceinline__ bf16x8 cvt8(f32x4 a, f32x4 b) {
    bf16x8 r;
    r[0] = (__bf16)a[0]; r[1] = (__bf16)a[1]; r[2] = (__bf16)a[2]; r[3] = (__bf16)a[3];
    r[4] = (__bf16)b[0]; r[5] = (__bf16)b[1]; r[6] = (__bf16)b[2]; r[7] = (__bf16)b[3];
    return r;
}

__global__ __launch_bounds__(256)
void prep_xc(const float* __restrict__ cat, const float* __restrict__ x,
             const float* __restrict__ hid, unsigned char* __restrict__ A0)
{
    int id  = blockIdx.x * 256 + threadIdx.x;
    int row = id >> 9, col = (id & 511) * 8;
    const float* src = (col < 512)  ? cat + (size_t)row * 512 + col
                     : (col < 2048) ? x   + (size_t)row * 1536 + (col - 512)
                                    : hid + (size_t)row * 2048 + (col - 2048);
    f32x4 a = *(const f32x4*)src, b = *(const f32x4*)(src + 4);
    int ks = col >> 6, c8 = (col & 63) >> 3;
    *(bf16x8*)(A0 + (size_t)ks * ATILE + swz(row, c8 * 16)) = cvt8(a, b);
}

// ===================== PRODUCTION GEMM (R4, frozen) =====================
template <int MODE>
__global__ __launch_bounds__(512, 2)
void gemm_bf16(const unsigned char* __restrict__ At,
               const float* __restrict__ W0, const float* __restrict__ W1,
               const float* __restrict__ W2, const float* __restrict__ W3,
               const float* __restrict__ B0, const float* __restrict__ B1,
               const float* __restrict__ B2, const float* __restrict__ B3,
               float* __restrict__ out, int ldout)
{
    __shared__ __align__(16) unsigned char lds[2 * ATILE + 2 * WTILE];

    constexpr int NKT = (MODE == 0) ? 32 : 64;

    const int tid  = threadIdx.x;
    const int lane = tid & 63;
    const int wid  = tid >> 6;
    const int l15  = lane & 15;
    const int l4   = lane >> 4;
    const int wr   = wid >> 1;
    const int wc   = wid & 1;

    int n0, koff; float* outp;
    if (MODE == 0) {
        n0 = (blockIdx.x >> 1) * 128;
        int kh = blockIdx.x & 1;
        koff = kh * 32;
        outp = out + (size_t)kh * 4194304;
    } else {
        n0 = blockIdx.x * 128; koff = 0; outp = out;
    }

    const float* Wsrc; const float* Bsrc; int wn0;
    if (MODE == 0) {
        int g = n0 >> 12;
        Wsrc = (g == 0) ? W0 : (g == 1) ? W1 : (g == 2) ? W2 : W3;
        Bsrc = (g == 0) ? B0 : (g == 1) ? B1 : (g == 2) ? B2 : B3;
        wn0  = n0 & 4095;
    } else {
        Wsrc = W0; Bsrc = B0; wn0 = n0;
    }

    f32x4 wreg[2][4];
    f32x4 acc[4][4] = {};

    const int wrow = tid >> 2;
    const int wkc  = tid & 3;
    const float* wbase = Wsrc + (size_t)(wn0 + wrow) * 4096 + (size_t)koff * 64 + wkc * 16;

    auto issueA = [&](int ks, int buf) {
        const unsigned char* src = At + (size_t)(koff + ks) * ATILE + wid * 4096 + lane * 16;
        unsigned char* dst = lds + buf * ATILE + wid * 4096;
        #pragma unroll
        for (int i = 0; i < 4; ++i)
            GLOAD_LDS16(src + i * 1024, dst + i * 1024);
    };
    auto loadW = [&](int ks, auto slot) {
        constexpr int S = decltype(slot)::v;
        const float* p = wbase + (size_t)ks * 64;
        wreg[S][0] = *(const f32x4*)p;
        wreg[S][1] = *(const f32x4*)(p + 4);
        wreg[S][2] = *(const f32x4*)(p + 8);
        wreg[S][3] = *(const f32x4*)(p + 12);
    };
    auto storeW = [&](auto slot, int buf) {
        constexpr int S = decltype(slot)::v;
        unsigned char* b = lds + LDS_W_OFF + buf * WTILE;
        *(bf16x8*)(b + swz(wrow, wkc * 32))      = cvt8(wreg[S][0], wreg[S][1]);
        *(bf16x8*)(b + swz(wrow, wkc * 32 + 16)) = cvt8(wreg[S][2], wreg[S][3]);
    };

    issueA(0, 0); loadW(0, IC<0>{});
    issueA(1, 1); loadW(1, IC<1>{});
    asm volatile("s_waitcnt vmcnt(8)" ::: "memory");
    SCHED();
    storeW(IC<0>{}, 0);
    asm volatile("s_waitcnt lgkmcnt(0)" ::: "memory");
    SBAR(); SCHED();

    auto step = [&](int t, auto curc) {
        constexpr int CUR = decltype(curc)::v;
        constexpr int OTH = CUR ^ 1;
        unsigned char* abase = lds + CUR * ATILE;
        unsigned char* wlds  = lds + LDS_W_OFF + CUR * WTILE;

        bf16x8 af[2][4], bw[2][4];
        #pragma unroll
        for (int kk = 0; kk < 2; ++kk) {
            #pragma unroll
            for (int m = 0; m < 4; ++m) {
                int row = wr * 64 + m * 16 + l15;
                af[kk][m] = *(const bf16x8*)(abase + swz(row, kk * 64 + l4 * 16));
            }
            #pragma unroll
            for (int n = 0; n < 4; ++n) {
                int row = wc * 64 + n * 16 + l15;
                bw[kk][n] = *(const bf16x8*)(wlds + swz(row, kk * 64 + l4 * 16));
            }
        }
        asm volatile("s_waitcnt lgkmcnt(0)" ::: "memory");
        SCHED(); SBAR(); SCHED();

        if (t + 2 < NKT) { issueA(t + 2, CUR); loadW(t + 2, curc); }
        #pragma unroll
        for (int kk = 0; kk < 2; ++kk)
            #pragma unroll
            for (int m = 0; m < 4; ++m)
                #pragma unroll
                for (int n = 0; n < 4; ++n)
                    acc[m][n] = __builtin_amdgcn_mfma_f32_16x16x32_bf16(
                        af[kk][m], bw[kk][n], acc[m][n], 0, 0, 0);
        if (t + 1 < NKT) {
            if (t + 2 < NKT) asm volatile("s_waitcnt vmcnt(8)" ::: "memory");
            else             asm volatile("s_waitcnt vmcnt(0)" ::: "memory");
            SCHED();
            storeW(IC<OTH>{}, OTH);
            asm volatile("s_waitcnt lgkmcnt(0)" ::: "memory");
        }
        SBAR(); SCHED();
    };

    for (int t = 0; t < NKT; t += 2) {
        step(t,     IC<0>{});
        step(t + 1, IC<1>{});
    }

    #pragma unroll
    for (int n = 0; n < 4; ++n) {
        int col = wc * 64 + n * 16 + l15;
        float bias = (MODE == 1 || koff == 0) ? Bsrc[wn0 + col] : 0.0f;
        #pragma unroll
        for (int m = 0; m < 4; ++m) {
            int row = wr * 64 + m * 16 + l4 * 4;
            f32x4 v = acc[m][n];
            #pragma unroll
            for (int j = 0; j < 4; ++j)
                outp[(size_t)(row + j) * ldout + n0 + col] = v[j] + bias;
        }
    }
}

__global__ __launch_bounds__(256)
void lstm_elem(const float* __restrict__ z0, const float* __restrict__ z1,
               const float* __restrict__ cell,
               float* __restrict__ cnew, float* __restrict__ hnew,
               unsigned char* __restrict__ A1)
{
    int id  = blockIdx.x * 256 + threadIdx.x;
    int row = id >> 9, col = (id & 511) * 8;
    const float* za = z0 + (size_t)row * 16384 + col;
    const float* zb = z1 + (size_t)row * 16384 + col;
    f32x4 vf[2], vi[2], vg[2], vo[2];
    #pragma unroll
    for (int h = 0; h < 2; ++h) {
        vf[h] = *(const f32x4*)(za + h * 4)         + *(const f32x4*)(zb + h * 4);
        vi[h] = *(const f32x4*)(za + 4096 + h * 4)  + *(const f32x4*)(zb + 4096 + h * 4);
        vg[h] = *(const f32x4*)(za + 8192 + h * 4)  + *(const f32x4*)(zb + 8192 + h * 4);
        vo[h] = *(const f32x4*)(za + 12288 + h * 4) + *(const f32x4*)(zb + 12288 + h * 4);
    }
    const float* cr = cell + (size_t)row * 4096 + col;
    f32x4 vc[2] = { *(const f32x4*)cr, *(const f32x4*)(cr + 4) };
    f32x4 rc[2], rh[2];
    bf16x8 hb;
    #pragma unroll
    for (int h = 0; h < 2; ++h)
        #pragma unroll
        for (int j = 0; j < 4; ++j) {
            float f = 1.0f / (1.0f + __expf(-vf[h][j]));
            float i = 1.0f / (1.0f + __expf(-vi[h][j]));
            float g = tanhf(vg[h][j]);
            float o = 1.0f / (1.0f + __expf(-vo[h][j]));
            float cn = f * vc[h][j] + i * g;
            float hn = o * tanhf(cn);
            rc[h][j] = cn; rh[h][j] = hn;
            hb[h * 4 + j] = (__bf16)hn;
        }
    float* cd = cnew + (size_t)row * 4096 + col;
    float* hd = hnew + (size_t)row * 4096 + col;
    *(f32x4*)cd = rc[0]; *(f32x4*)(cd + 4) = rc[1];
    *(f32x4*)hd = rh[0]; *(f32x4*)(hd + 4) = rh[1];
    int ks = col >> 6, c8 = (col & 63) >> 3;
    *(bf16x8*)(A1 + (size_t)ks * ATILE + swz(row, c8 * 16)) = hb;
}

__global__ __launch_bounds__(256)
void logsoftmax_inplace(float* __restrict__ out)
{
    float* row    = out + (size_t)blockIdx.x * 32000;
    const int tid = threadIdx.x;
    __shared__ float redm[4], reds[4];

    float m = -1e30f, s = 0.0f;
    for (int i = tid; i < 8000; i += 256) {
        f32x4 v = *(const f32x4*)(row + i * 4);
        float t = fmaxf(fmaxf(v[0], v[1]), fmaxf(v[2], v[3]));
        float nm = fmaxf(m, t);
        s = s * __expf(m - nm) + __expf(v[0] - nm) + __expf(v[1] - nm)
                               + __expf(v[2] - nm) + __expf(v[3] - nm);
        m = nm;
    }
    #pragma unroll
    for (int off = 32; off; off >>= 1) {
        float om = __shfl_xor(m, off), os = __shfl_xor(s, off);
        float nm = fmaxf(m, om);
        s = s * __expf(m - nm) + os * __expf(om - nm);
        m = nm;
    }
    if ((tid & 63) == 0) { redm[tid >> 6] = m; reds[tid >> 6] = s; }
    __syncthreads();
    {
        float M = fmaxf(fmaxf(redm[0], redm[1]), fmaxf(redm[2], redm[3]));
        float S = reds[0] * __expf(redm[0] - M) + reds[1] * __expf(redm[1] - M)
                + reds[2] * __expf(redm[2] - M) + reds[3] * __expf(redm[3] - M);
        m = M; s = S;
    }
    float lse = m + logf(s);

    for (int i = tid; i < 8000; i += 256) {
        f32x4 v = *(const f32x4*)(row + i * 4);
        v[0] -= lse; v[1] -= lse; v[2] -= lse; v[3] -= lse;
        *(f32x4*)(row + i * 4) = v;
    }
}

// ===================== DIAGNOSTIC PROBES (outputs -> dead ws) =====================
// VAR 0: drain-per-step GEMM (R2 structure).  VAR 1: clean counted-vmcnt GEMM.
// VAR 3: consumption-only (no W stream).
template <int VAR, int REP>
__global__ __launch_bounds__(512, 2)
void probe_gemm(const unsigned char* __restrict__ At, const float* __restrict__ W,
                float* __restrict__ dump)
{
    __shared__ __align__(16) unsigned char lds[2 * ATILE + 2 * WTILE];
    const int tid  = threadIdx.x;
    const int lane = tid & 63, wid = tid >> 6;
    const int l15  = lane & 15, l4 = lane >> 4;
    const int wr   = wid >> 1,  wc = wid & 1;
    const int wrow = tid >> 2,  wkc = tid & 3;

    f32x4 wreg[2][4];
    f32x4 acc[4][4] = {};

    if constexpr (VAR == 3) {
        for (int i = tid; i < (2 * WTILE) / 16; i += 512)
            *(f32x4*)(lds + LDS_W_OFF + i * 16) = f32x4{0, 0, 0, 0};
        __syncthreads();
    }

    for (int r = 0; r < REP; ++r) {
        const int n0 = ((blockIdx.x + r * 83) % 250) * 128;
        const float* wbase = W + (size_t)(n0 + wrow) * 4096 + wkc * 16;

        auto issueA = [&](int ks, int buf) {
            const unsigned char* src = At + (size_t)ks * ATILE + wid * 4096 + lane * 16;
            unsigned char* dst = lds + buf * ATILE + wid * 4096;
            #pragma unroll
            for (int i = 0; i < 4; ++i)
                GLOAD_LDS16(src + i * 1024, dst + i * 1024);
        };
        auto loadW = [&](int ks, auto slot) {
            constexpr int S = decltype(slot)::v;
            const float* p = wbase + (size_t)ks * 64;
            wreg[S][0] = *(const f32x4*)p;       wreg[S][1] = *(const f32x4*)(p + 4);
            wreg[S][2] = *(const f32x4*)(p + 8); wreg[S][3] = *(const f32x4*)(p + 12);
        };
        auto storeW = [&](auto slot, int buf) {
            constexpr int S = decltype(slot)::v;
            unsigned char* b = lds + LDS_W_OFF + buf * WTILE;
            *(bf16x8*)(b + swz(wrow, wkc * 32))      = cvt8(wreg[S][0], wreg[S][1]);
            *(bf16x8*)(b + swz(wrow, wkc * 32 + 16)) = cvt8(wreg[S][2], wreg[S][3]);
        };
        auto rdfrags = [&](int CUR, bf16x8 (&af)[2][4], bf16x8 (&bw)[2][4]) {
            const unsigned char* abase = lds + CUR * ATILE;
            const unsigned char* wlds  = lds + LDS_W_OFF + ((VAR == 3) ? 0 : CUR) * WTILE;
            #pragma unroll
            for (int kk = 0; kk < 2; ++kk) {
                #pragma unroll
                for (int m = 0; m < 4; ++m) {
                    int row = wr * 64 + m * 16 + l15;
                    af[kk][m] = *(const bf16x8*)(abase + swz(row, kk * 64 + l4 * 16));
                }
                #pragma unroll
                for (int n = 0; n < 4; ++n) {
                    int row = wc * 64 + n * 16 + l15;
                    bw[kk][n] = *(const bf16x8*)(wlds + swz(row, kk * 64 + l4 * 16));
                }
            }
        };
        auto mfma8 = [&](bf16x8 (&af)[2][4], bf16x8 (&bw)[2][4]) {
            #pragma unroll
            for (int kk = 0; kk < 2; ++kk)
                #pragma unroll
                for (int m = 0; m < 4; ++m)
                    #pragma unroll
                    for (int n = 0; n < 4; ++n)
                        acc[m][n] = __builtin_amdgcn_mfma_f32_16x16x32_bf16(
                            af[kk][m], bw[kk][n], acc[m][n], 0, 0, 0);
        };

        if constexpr (VAR == 0) {
            issueA(0, 0); loadW(0, IC<0>{});
            storeW(IC<0>{}, 0);
            __syncthreads();
            auto stepD = [&](int t, auto curc) {
                constexpr int CUR = decltype(curc)::v;
                if (t + 1 < 64) { issueA(t + 1, CUR ^ 1); loadW(t + 1, IC<CUR ^ 1>{}); }
                bf16x8 af[2][4], bw[2][4];
                rdfrags(CUR, af, bw);
                mfma8(af, bw);
                if (t + 1 < 64) storeW(IC<CUR ^ 1>{}, CUR ^ 1);
                __syncthreads();
            };
            for (int t = 0; t < 64; t += 2) { stepD(t, IC<0>{}); stepD(t + 1, IC<1>{}); }
        } else if constexpr (VAR == 1) {
            issueA(0, 0); loadW(0, IC<0>{});
            issueA(1, 1); loadW(1, IC<1>{});
            asm volatile("s_waitcnt vmcnt(8)" ::: "memory"); SCHED();
            storeW(IC<0>{}, 0);
            asm volatile("s_waitcnt lgkmcnt(0)" ::: "memory");
            SBAR(); SCHED();
            auto stepC = [&](int t, auto curc) {
                constexpr int CUR = decltype(curc)::v;
                bf16x8 af[2][4], bw[2][4];
                rdfrags(CUR, af, bw);
                asm volatile("s_waitcnt lgkmcnt(0)" ::: "memory");
                SCHED(); SBAR(); SCHED();
                if (t + 2 < 64) { issueA(t + 2, CUR); loadW(t + 2, curc); }
                mfma8(af, bw);
                if (t + 1 < 64) {
                    if (t + 2 < 64) asm volatile("s_waitcnt vmcnt(8)" ::: "memory");
                    else            asm volatile("s_waitcnt vmcnt(0)" ::: "memory");
                    SCHED();
                    storeW(IC<CUR ^ 1>{}, CUR ^ 1);
                    asm volatile("s_waitcnt lgkmcnt(0)" ::: "memory");
                }
                SBAR(); SCHED();
            };
            for (int t = 0; t < 64; t += 2) { stepC(t, IC<0>{}); stepC(t + 1, IC<1>{}); }
        } else {   // VAR == 3: consumption only
            issueA(0, 0); issueA(1, 1);
            asm volatile("s_waitcnt vmcnt(4)" ::: "memory"); SCHED();
            SBAR(); SCHED();
            auto step3 = [&](int t, auto curc) {
                constexpr int CUR = decltype(curc)::v;
                bf16x8 af[2][4], bw[2][4];
                rdfrags(CUR, af, bw);
                asm volatile("s_waitcnt lgkmcnt(0)" ::: "memory");
                SCHED(); SBAR(); SCHED();
                if (t + 2 < 64) issueA(t + 2, CUR);
                mfma8(af, bw);
                if (t + 2 < 64) asm volatile("s_waitcnt vmcnt(4)" ::: "memory");
                else            asm volatile("s_waitcnt vmcnt(0)" ::: "memory");
                SCHED(); SBAR(); SCHED();
            };
            for (int t = 0; t < 64; t += 2) { step3(t, IC<0>{}); step3(t + 1, IC<1>{}); }
        }
    }

    float s = 0.0f;
    #pragma unroll
    for (int m = 0; m < 4; ++m)
        #pragma unroll
        for (int n = 0; n < 4; ++n)
            s += acc[m][n][0] + acc[m][n][1] + acc[m][n][2] + acc[m][n][3];
    dump[(size_t)blockIdx.x * 512 + tid] = s;
}

// VAR 2: production access pattern (64B/thread, 512B stride).  VAR 4: wave-linear 1KB bursts.
template <int VAR, int REP>
__global__ __launch_bounds__(512)
void probe_stream(const float* __restrict__ W, float* __restrict__ dump)
{
    const int tid = threadIdx.x;
    f32x4 s[8] = {};
    for (int r = 0; r < REP; ++r) {
        const int n0 = ((blockIdx.x + r * 211) % 500) * 64;
        if constexpr (VAR == 2) {
            const int wrow = tid >> 3, wkc = tid & 7;   // 64 rows x 8 chunks x 16 floats
            const float* wb = W + (size_t)(n0 + wrow) * 4096 + wkc * 16;
            for (int ks = 0; ks < 32; ks += 2) {
                const float* p = wb + (size_t)ks * 128;
                s[0] += *(const f32x4*)(p);       s[1] += *(const f32x4*)(p + 4);
                s[2] += *(const f32x4*)(p + 8);   s[3] += *(const f32x4*)(p + 12);
                s[4] += *(const f32x4*)(p + 128); s[5] += *(const f32x4*)(p + 132);
                s[6] += *(const f32x4*)(p + 136); s[7] += *(const f32x4*)(p + 140);
            }
        } else {   // VAR 4: wave w reads rows w, w+8, ... in full-wave 1KB bursts
            const int wid = tid >> 6, lane = tid & 63;
            for (int r8 = 0; r8 < 8; ++r8) {
                const int row = r8 * 8 + wid;
                const float* p = W + (size_t)(n0 + row) * 4096 + lane * 4;
                #pragma unroll
                for (int b = 0; b < 16; b += 4) {
                    s[0] += *(const f32x4*)(p + (b + 0) * 256);
                    s[1] += *(const f32x4*)(p + (b + 1) * 256);
                    s[2] += *(const f32x4*)(p + (b + 2) * 256);
                    s[3] += *(const f32x4*)(p + (b + 3) * 256);
                }
            }
        }
    }
    f32x4 t = s[0] + s[1] + s[2] + s[3] + s[4] + s[5] + s[6] + s[7];
    dump[(size_t)blockIdx.x * 512 + tid] = t[0] + t[1] + t[2] + t[3];
}

extern "C" void kernel_launch(void* const* d_in, const int* in_sizes, int n_in,
                              void* d_out, int out_size, void* d_ws, size_t ws_size,
                              hipStream_t stream)
{
    const float* cat  = (const float*)d_in[0];
    const float* x    = (const float*)d_in[1];
    const float* hid  = (const float*)d_in[2];
    const float* cell = (const float*)d_in[3];
    const float* Wf   = (const float*)d_in[4];
    const float* bf   = (const float*)d_in[5];
    const float* Wi   = (const float*)d_in[6];
    const float* bi   = (const float*)d_in[7];
    const float* Wc   = (const float*)d_in[8];
    const float* bc   = (const float*)d_in[9];
    const float* Wo   = (const float*)d_in[10];
    const float* bo   = (const float*)d_in[11];
    const float* Wout = (const float*)d_in[12];
    const float* bout = (const float*)d_in[13];
    float* out = (float*)d_out;

    // ws: A0 (2MB) | A1 (2MB) | z0 (16MB) | z1 (16MB) | probe dump (>=40MB offset)
    unsigned char* A0 = (unsigned char*)d_ws;
    unsigned char* A1 = A0 + (size_t)64 * ATILE;
    float*         z  = (float*)(A1 + (size_t)64 * ATILE);
    float*       dump = (float*)((unsigned char*)d_ws + ((size_t)40 << 20));

    float* cnew = out + 8192000;
    float* hnew = out + 9240576;

    // -------- production (R4, frozen) --------
    prep_xc<<<512, 256, 0, stream>>>(cat, x, hid, A0);
    gemm_bf16<0><<<256, 512, 0, stream>>>(A0, Wf, Wi, Wc, Wo, bf, bi, bc, bo, z, 16384);
    lstm_elem<<<512, 256, 0, stream>>>(z, z + 4194304, cell, cnew, hnew, A1);
    gemm_bf16<1><<<250, 512, 0, stream>>>(A1, Wout, Wout, Wout, Wout,
                                          bout, bout, bout, bout, out, 32000);
    logsoftmax_inplace<<<256, 256, 0, stream>>>(out);

    // -------- diagnostic probes (top-5-visible; outputs dead) --------
    probe_gemm<0, 3><<<250, 512, 0, stream>>>(A0, Wout, dump);            // drain baseline
    probe_gemm<1, 3><<<250, 512, 0, stream>>>(A0, Wout, dump + 131072);   // counted vmcnt
    probe_gemm<3, 12><<<250, 512, 0, stream>>>(A0, Wout, dump + 262144);  // consumption only
    probe_stream<2, 6><<<500, 512, 0, stream>>>(Wout, dump + 393216);     // pattern stream
    probe_stream<4, 6><<<500, 512, 0, stream>>>(Wout, dump + 655360);     // wave-linear stream
}

// Round 10
// 1152.337 us; speedup vs baseline: 2.2720x; 2.2720x over previous
//
#include <hip/hip_runtime.h>
#include <cmath>

typedef __bf16 bf16x8 __attribute__((ext_vector_type(8)));
typedef float  f32x4  __attribute__((ext_vector_type(4)));

template <int N> struct IC { static constexpr int v = N; };

#define ATILE 32768   // one K-tile of A: 256 rows * 128 B (bf16, plain row-major)
#define WBUF  16384   // one W window in LDS: 64 rows * 256 B (bf16, swizzled)

#define SBAR()  __builtin_amdgcn_s_barrier()
#define SCHED() __builtin_amdgcn_sched_barrier(0)

__device__ __forceinline__ bf16x8 cvt8(f32x4 a, f32x4 b) {
    bf16x8 r;
    r[0] = (__bf16)a[0]; r[1] = (__bf16)a[1]; r[2] = (__bf16)a[2]; r[3] = (__bf16)a[3];
    r[4] = (__bf16)b[0]; r[5] = (__bf16)b[1]; r[6] = (__bf16)b[2]; r[7] = (__bf16)b[3];
    return r;
}

// A0 = concat(cat,x,hid) bf16, K-tiled [ks][row][64 cols], plain layout.
__global__ __launch_bounds__(256)
void prep_xc(const float* __restrict__ cat, const float* __restrict__ x,
             const float* __restrict__ hid, unsigned char* __restrict__ A0)
{
    int id  = blockIdx.x * 256 + threadIdx.x;
    int row = id >> 9, col = (id & 511) * 8;
    const float* src = (col < 512)  ? cat + (size_t)row * 512 + col
                     : (col < 2048) ? x   + (size_t)row * 1536 + (col - 512)
                                    : hid + (size_t)row * 2048 + (col - 2048);
    f32x4 a = *(const f32x4*)src, b = *(const f32x4*)(src + 4);
    *(bf16x8*)(A0 + (size_t)(col >> 6) * ATILE + row * 128 + (col & 63) * 2) = cvt8(a, b);
}

// A-from-L2 GEMM: 256 thr = 4 waves, each wave = 64 M-rows x all 64 N-cols.
// A fragments stream directly global(L2)->VGPR (no LDS). W streams through a
// 2-deep LDS window pipeline (64 rows x 128 K per window, 2 K-steps/window);
// one raw s_barrier per window; NO hand-written vmcnt -- compiler reg-dep
// counting keeps both streams in flight across barriers.
// MODE 0: gates, split-K x2 -> 512 blocks, out z0/z1 (bias on half 0).
// MODE 1: vocab, 500 blocks, out logits + bias.
template <int MODE>
__global__ __launch_bounds__(256, 2)
void gemm_l2a(const unsigned char* __restrict__ At,
              const float* __restrict__ W0, const float* __restrict__ W1,
              const float* __restrict__ W2, const float* __restrict__ W3,
              const float* __restrict__ B0, const float* __restrict__ B1,
              const float* __restrict__ B2, const float* __restrict__ B3,
              float* __restrict__ out, int ldout)
{
    constexpr int NKT = (MODE == 0) ? 32 : 64;   // K-steps (BK=64)
    constexpr int NW  = NKT / 2;                 // windows (128 K each)

    __shared__ __align__(16) unsigned char lds[2 * WBUF];

    const int tid  = threadIdx.x;
    const int lane = tid & 63;
    const int wid  = tid >> 6;
    const int l15  = lane & 15;
    const int l4   = lane >> 4;

    int n0, koff; float* outp;
    if constexpr (MODE == 0) {
        n0   = (blockIdx.x >> 1) * 64;
        int kh = blockIdx.x & 1;
        koff = kh * 32;
        outp = out + (size_t)kh * 4194304;       // z0 / z1
    } else {
        n0 = blockIdx.x * 64; koff = 0; outp = out;
    }

    const float* Wsrc; const float* Bsrc; int wn0;
    if constexpr (MODE == 0) {
        int g = n0 >> 12;
        Wsrc = (g == 0) ? W0 : (g == 1) ? W1 : (g == 2) ? W2 : W3;
        Bsrc = (g == 0) ? B0 : (g == 1) ? B1 : (g == 2) ? B2 : B3;
        wn0  = n0 & 4095;
    } else {
        Wsrc = W0; Bsrc = B0; wn0 = n0;
    }

    // ---- W staging: 256 thr = 64 rows x 4 col-chunks of 32 floats ----
    const int rw = tid >> 2, ci = tid & 3;
    const float* wrow = Wsrc + (size_t)(wn0 + rw) * 4096 + (size_t)koff * 64 + ci * 32;
    const int sw = (rw & 7) << 4;

    f32x4 wrA[8], wrB[8];                        // window reg sets (static names)
    auto loadWreg = [&](int w, f32x4 (&r)[8]) {
        const float* p = wrow + w * 128;
        #pragma unroll
        for (int i = 0; i < 8; ++i) r[i] = *(const f32x4*)(p + i * 4);
    };
    auto writeW = [&](f32x4 (&r)[8], int buf) {
        unsigned char* b = lds + buf * WBUF + rw * 256;
        #pragma unroll
        for (int j = 0; j < 4; ++j)
            *(bf16x8*)(b + ((ci * 64 + j * 16) ^ sw)) = cvt8(r[2 * j], r[2 * j + 1]);
    };

    // ---- A fragments: direct from L2 (plain bf16 image) ----
    const unsigned char* abase = At + (size_t)(wid * 64 + l15) * 128 + l4 * 16;
    auto issueA = [&](int t, bf16x8 (&af)[2][4]) {
        const unsigned char* p = abase + (size_t)(koff + t) * ATILE;
        #pragma unroll
        for (int kk = 0; kk < 2; ++kk)
            #pragma unroll
            for (int m = 0; m < 4; ++m)
                af[kk][m] = *(const bf16x8*)(p + m * 2048 + kk * 64);
    };

    f32x4 acc[4][4] = {};
    auto mfmastep = [&](int buf, int s, bf16x8 (&af)[2][4]) {
        const unsigned char* b = lds + buf * WBUF;
        #pragma unroll
        for (int kk = 0; kk < 2; ++kk) {
            bf16x8 bw[4];
            #pragma unroll
            for (int n = 0; n < 4; ++n) {
                const int row = n * 16 + l15;
                bw[n] = *(const bf16x8*)(b + row * 256 +
                          ((s * 128 + kk * 64 + l4 * 16) ^ ((row & 7) << 4)));
            }
            #pragma unroll
            for (int m = 0; m < 4; ++m)
                #pragma unroll
                for (int n = 0; n < 4; ++n)
                    acc[m][n] = __builtin_amdgcn_mfma_f32_16x16x32_bf16(
                        af[kk][m], bw[n], acc[m][n], 0, 0, 0);
        }
    };

    bf16x8 afA[2][4], afB[2][4];

    // prologue: win0,win1 W-regs + steps 0,1 A-frags in flight; win0 -> LDS
    loadWreg(0, wrA); loadWreg(1, wrB);
    issueA(0, afA); issueA(1, afB);
    writeW(wrA, 0);
    asm volatile("s_waitcnt lgkmcnt(0)" ::: "memory");
    SCHED(); SBAR(); SCHED();

    auto window = [&](int w, auto bufc, f32x4 (&wrNext)[8], f32x4 (&wrRef)[8]) {
        constexpr int BUF = decltype(bufc)::v;
        if (w + 1 < NW) writeW(wrNext, BUF ^ 1);   // compiler waits exactly these regs
        if (w + 2 < NW) loadWreg(w + 2, wrRef);    // refill freed set (stays in flight)
        mfmastep(BUF, 0, afA);
        if (2 * w + 2 < NKT) issueA(2 * w + 2, afA);
        mfmastep(BUF, 1, afB);
        if (2 * w + 3 < NKT) issueA(2 * w + 3, afB);
        asm volatile("s_waitcnt lgkmcnt(0)" ::: "memory");
        SCHED(); SBAR(); SCHED();
    };

    for (int w = 0; w < NW; w += 2) {
        window(w,     IC<0>{}, wrB, wrA);
        window(w + 1, IC<1>{}, wrA, wrB);
    }

    // epilogue: C/D map col=lane&15, row=(lane>>4)*4+j
    #pragma unroll
    for (int n = 0; n < 4; ++n) {
        const int col = n0 + n * 16 + l15;
        const float bias = (MODE == 1 || koff == 0) ? Bsrc[wn0 + n * 16 + l15] : 0.0f;
        #pragma unroll
        for (int m = 0; m < 4; ++m) {
            const int row = wid * 64 + m * 16 + l4 * 4;
            f32x4 v = acc[m][n];
            #pragma unroll
            for (int j = 0; j < 4; ++j)
                outp[(size_t)(row + j) * ldout + col] = v[j] + bias;
        }
    }
}

// gates (z0+z1) -> cell_new/hidden_new + bf16 plain-tiled hidden for gemm1
__global__ __launch_bounds__(256)
void lstm_elem(const float* __restrict__ z0, const float* __restrict__ z1,
               const float* __restrict__ cell,
               float* __restrict__ cnew, float* __restrict__ hnew,
               unsigned char* __restrict__ A1)
{
    int id  = blockIdx.x * 256 + threadIdx.x;
    int row = id >> 9, col = (id & 511) * 8;
    const float* za = z0 + (size_t)row * 16384 + col;
    const float* zb = z1 + (size_t)row * 16384 + col;
    f32x4 vf[2], vi[2], vg[2], vo[2];
    #pragma unroll
    for (int h = 0; h < 2; ++h) {
        vf[h] = *(const f32x4*)(za + h * 4)         + *(const f32x4*)(zb + h * 4);
        vi[h] = *(const f32x4*)(za + 4096 + h * 4)  + *(const f32x4*)(zb + 4096 + h * 4);
        vg[h] = *(const f32x4*)(za + 8192 + h * 4)  + *(const f32x4*)(zb + 8192 + h * 4);
        vo[h] = *(const f32x4*)(za + 12288 + h * 4) + *(const f32x4*)(zb + 12288 + h * 4);
    }
    const float* cr = cell + (size_t)row * 4096 + col;
    f32x4 vc[2] = { *(const f32x4*)cr, *(const f32x4*)(cr + 4) };
    f32x4 rc[2], rh[2];
    bf16x8 hb;
    #pragma unroll
    for (int h = 0; h < 2; ++h)
        #pragma unroll
        for (int j = 0; j < 4; ++j) {
            float f = 1.0f / (1.0f + __expf(-vf[h][j]));
            float i = 1.0f / (1.0f + __expf(-vi[h][j]));
            float g = tanhf(vg[h][j]);
            float o = 1.0f / (1.0f + __expf(-vo[h][j]));
            float cn = f * vc[h][j] + i * g;
            float hn = o * tanhf(cn);
            rc[h][j] = cn; rh[h][j] = hn;
            hb[h * 4 + j] = (__bf16)hn;
        }
    float* cd = cnew + (size_t)row * 4096 + col;
    float* hd = hnew + (size_t)row * 4096 + col;
    *(f32x4*)cd = rc[0]; *(f32x4*)(cd + 4) = rc[1];
    *(f32x4*)hd = rh[0]; *(f32x4*)(hd + 4) = rh[1];
    *(bf16x8*)(A1 + (size_t)(col >> 6) * ATILE + row * 128 + (col & 63) * 2) = hb;
}

__global__ __launch_bounds__(256)
void logsoftmax_inplace(float* __restrict__ out)
{
    float* row    = out + (size_t)blockIdx.x * 32000;
    const int tid = threadIdx.x;
    __shared__ float redm[4], reds[4];

    float m = -1e30f, s = 0.0f;
    for (int i = tid; i < 8000; i += 256) {
        f32x4 v = *(const f32x4*)(row + i * 4);
        float t = fmaxf(fmaxf(v[0], v[1]), fmaxf(v[2], v[3]));
        float nm = fmaxf(m, t);
        s = s * __expf(m - nm) + __expf(v[0] - nm) + __expf(v[1] - nm)
                               + __expf(v[2] - nm) + __expf(v[3] - nm);
        m = nm;
    }
    #pragma unroll
    for (int off = 32; off; off >>= 1) {
        float om = __shfl_xor(m, off), os = __shfl_xor(s, off);
        float nm = fmaxf(m, om);
        s = s * __expf(m - nm) + os * __expf(om - nm);
        m = nm;
    }
    if ((tid & 63) == 0) { redm[tid >> 6] = m; reds[tid >> 6] = s; }
    __syncthreads();
    {
        float M = fmaxf(fmaxf(redm[0], redm[1]), fmaxf(redm[2], redm[3]));
        float S = reds[0] * __expf(redm[0] - M) + reds[1] * __expf(redm[1] - M)
                + reds[2] * __expf(redm[2] - M) + reds[3] * __expf(redm[3] - M);
        m = M; s = S;
    }
    float lse = m + logf(s);

    for (int i = tid; i < 8000; i += 256) {
        f32x4 v = *(const f32x4*)(row + i * 4);
        v[0] -= lse; v[1] -= lse; v[2] -= lse; v[3] -= lse;
        *(f32x4*)(row + i * 4) = v;
    }
}

// Single probe (will own the top-5): W-staging DRAM pattern in isolation.
// 500 blocks x 64-row panel; per rep, sweep K in 32 windows of 512B/row.
template <int REP>
__global__ __launch_bounds__(256)
void probe_wstream(const float* __restrict__ W, float* __restrict__ dump)
{
    const int tid = threadIdx.x;
    const int rw = tid >> 2, ci = tid & 3;
    f32x4 s[8] = {};
    for (int r = 0; r < REP; ++r) {
        const int n0 = (int)(((blockIdx.x + (unsigned)r * 211u) % 500u) * 64u);
        const float* wrow = W + (size_t)(n0 + rw) * 4096 + ci * 32;
        for (int w = 0; w < 32; ++w) {
            const float* p = wrow + w * 128;
            #pragma unroll
            for (int i = 0; i < 8; ++i) s[i] += *(const f32x4*)(p + i * 4);
        }
    }
    f32x4 t = s[0] + s[1] + s[2] + s[3] + s[4] + s[5] + s[6] + s[7];
    dump[(size_t)blockIdx.x * 256 + tid] = t[0] + t[1] + t[2] + t[3];
}

extern "C" void kernel_launch(void* const* d_in, const int* in_sizes, int n_in,
                              void* d_out, int out_size, void* d_ws, size_t ws_size,
                              hipStream_t stream)
{
    const float* cat  = (const float*)d_in[0];
    const float* x    = (const float*)d_in[1];
    const float* hid  = (const float*)d_in[2];
    const float* cell = (const float*)d_in[3];
    const float* Wf   = (const float*)d_in[4];
    const float* bf   = (const float*)d_in[5];
    const float* Wi   = (const float*)d_in[6];
    const float* bi   = (const float*)d_in[7];
    const float* Wc   = (const float*)d_in[8];
    const float* bc   = (const float*)d_in[9];
    const float* Wo   = (const float*)d_in[10];
    const float* bo   = (const float*)d_in[11];
    const float* Wout = (const float*)d_in[12];
    const float* bout = (const float*)d_in[13];
    float* out = (float*)d_out;

    // ws: A0 (2MB) | A1 (2MB) | z0 (16MB) | z1 (16MB) | dump @40MB
    unsigned char* A0 = (unsigned char*)d_ws;
    unsigned char* A1 = A0 + (size_t)64 * ATILE;
    float*         z  = (float*)(A1 + (size_t)64 * ATILE);
    float*       dump = (float*)((unsigned char*)d_ws + ((size_t)40 << 20));

    // d_out: [logits 256x32000 | cell_new 256x4096 | hidden_new 256x4096]
    float* cnew = out + 8192000;
    float* hnew = out + 9240576;

    prep_xc<<<512, 256, 0, stream>>>(cat, x, hid, A0);
    // gates GEMM (split-K x2): 512 blocks x 64 cols
    gemm_l2a<0><<<512, 256, 0, stream>>>(A0, Wf, Wi, Wc, Wo, bf, bi, bc, bo, z, 16384);
    lstm_elem<<<512, 256, 0, stream>>>(z, z + 4194304, cell, cnew, hnew, A1);
    // vocab GEMM: 500 blocks x 64 cols
    gemm_l2a<1><<<500, 256, 0, stream>>>(A1, Wout, nullptr, nullptr, nullptr,
                                         bout, nullptr, nullptr, nullptr, out, 32000);
    logsoftmax_inplace<<<256, 256, 0, stream>>>(out);

    // diagnostic: W-stream pattern BW (4 GB; owns the top-5 counters)
    probe_wstream<8><<<500, 256, 0, stream>>>(Wout, dump);
}

// Round 11
// 1134.246 us; speedup vs baseline: 2.3082x; 1.0160x over previous
//
#include <hip/hip_runtime.h>
#include <cmath>

typedef __bf16 bf16x8 __attribute__((ext_vector_type(8)));
typedef float  f32x4  __attribute__((ext_vector_type(4)));

#define ATILE 32768        // one K-tile of A: 256 rows * 128 B (bf16, plain)
#define NW    8            // windows per GEMM (K=4096 / 512)
#define WIN_K 512          // K floats per window
#define WROWB 1024         // LDS bytes per row per window (512 bf16)
#define WBUF  (64 * WROWB) // 64 KB window buffer

#define SBAR()  __builtin_amdgcn_s_barrier()
#define SCHED() __builtin_amdgcn_sched_barrier(0)

__device__ __forceinline__ bf16x8 cvt8(f32x4 a, f32x4 b) {
    bf16x8 r;
    r[0] = (__bf16)a[0]; r[1] = (__bf16)a[1]; r[2] = (__bf16)a[2]; r[3] = (__bf16)a[3];
    r[4] = (__bf16)b[0]; r[5] = (__bf16)b[1]; r[6] = (__bf16)b[2]; r[7] = (__bf16)b[3];
    return r;
}

// A0 = concat(cat,x,hid) bf16, K-tiled [ks][row][64 cols], plain layout.
__global__ __launch_bounds__(256)
void prep_xc(const float* __restrict__ cat, const float* __restrict__ x,
             const float* __restrict__ hid, unsigned char* __restrict__ A0)
{
    int id  = blockIdx.x * 256 + threadIdx.x;
    int row = id >> 9, col = (id & 511) * 8;
    const float* src = (col < 512)  ? cat + (size_t)row * 512 + col
                     : (col < 2048) ? x   + (size_t)row * 1536 + (col - 512)
                                    : hid + (size_t)row * 2048 + (col - 2048);
    f32x4 a = *(const f32x4*)src, b = *(const f32x4*)(src + 4);
    *(bf16x8*)(A0 + (size_t)(col >> 6) * ATILE + row * 128 + (col & 63) * 2) = cvt8(a, b);
}

// Producer/consumer GEMM, 768 thr = 12 waves.
//   waves 0-3  (consumers): 64 M-rows each x BN=64; A-frags L2->VGPR (own FIFO),
//                           B-frags from LDS window, MFMA.
//   waves 4-11 (producers): 8 consecutive W-rows each; per window read 2 KB
//                           CONTIGUOUS per row (fp32), cvt->swizzled LDS.
// One raw s_barrier per window; producers' vmcnt FIFO carries only W loads.
// MODE 0: gates (256 blocks, gate = n0>>12), z out. MODE 1: vocab (500 blocks).
template <int MODE>
__global__ __launch_bounds__(768, 1)
void gemm_pc(const unsigned char* __restrict__ At,
             const float* __restrict__ W0, const float* __restrict__ W1,
             const float* __restrict__ W2, const float* __restrict__ W3,
             const float* __restrict__ B0, const float* __restrict__ B1,
             const float* __restrict__ B2, const float* __restrict__ B3,
             float* __restrict__ out, int ldout)
{
    __shared__ __align__(16) unsigned char lds[2 * WBUF];   // 128 KB

    const int tid  = threadIdx.x;
    const int lane = tid & 63;
    const int wid  = tid >> 6;          // 0..11
    const int l15  = lane & 15;
    const int l4   = lane >> 4;

    const int n0 = blockIdx.x * 64;
    const float* Wsrc; const float* Bsrc; int wn0;
    if constexpr (MODE == 0) {
        int g = n0 >> 12;
        Wsrc = (g == 0) ? W0 : (g == 1) ? W1 : (g == 2) ? W2 : W3;
        Bsrc = (g == 0) ? B0 : (g == 1) ? B1 : (g == 2) ? B2 : B3;
        wn0  = n0 & 4095;
    } else {
        Wsrc = W0; Bsrc = B0; wn0 = n0;
    }

    if (wid >= 4) {
        // ---------------- producers ----------------
        const int r0 = (wid - 4) * 8;                  // rows r0..r0+7 (consecutive)
        f32x4 pr[16];                                  // 8 rows x 2 f32x4 (static idx)
        auto issueW = [&](int w) {
            #pragma unroll
            for (int r = 0; r < 8; ++r) {
                const float* p = Wsrc + (size_t)(wn0 + r0 + r) * 4096
                               + (size_t)w * WIN_K + lane * 8;
                pr[2 * r]     = *(const f32x4*)p;      // 2 sweeps cover the row's
                pr[2 * r + 1] = *(const f32x4*)(p + 4);// 2 KB contiguous chunk
            }
        };
        auto writeW = [&](int w) {
            unsigned char* b = lds + (w & 1) * WBUF;
            #pragma unroll
            for (int r = 0; r < 8; ++r) {
                const int row = r0 + r;
                *(bf16x8*)(b + row * WROWB + ((lane * 16) ^ ((row & 7) << 4))) =
                    cvt8(pr[2 * r], pr[2 * r + 1]);    // compiler waits pr regs
            }
        };
        issueW(0);
        writeW(0);
        asm volatile("s_waitcnt lgkmcnt(0)" ::: "memory");
        SCHED(); SBAR(); SCHED();                      // window 0 ready
        for (int w = 0; w < NW; ++w) {
            if (w + 1 < NW) {
                issueW(w + 1);                         // 2 KB/row burst in flight
                writeW(w + 1);                         // vmcnt waits via reg deps
                asm volatile("s_waitcnt lgkmcnt(0)" ::: "memory");
            }
            SCHED(); SBAR(); SCHED();                  // consumers done w / w+1 ready
        }
    } else {
        // ---------------- consumers ----------------
        const unsigned char* abase = At + (size_t)(wid * 64 + l15) * 128 + l4 * 16;
        auto issueA = [&](int t, bf16x8 (&af)[2][4]) {
            const unsigned char* p = abase + (size_t)t * ATILE;
            #pragma unroll
            for (int kk = 0; kk < 2; ++kk)
                #pragma unroll
                for (int m = 0; m < 4; ++m)
                    af[kk][m] = *(const bf16x8*)(p + m * 2048 + kk * 64);
        };
        f32x4 acc[4][4] = {};
        auto kstep = [&](const unsigned char* buf, int s, bf16x8 (&af)[2][4]) {
            #pragma unroll
            for (int kk = 0; kk < 2; ++kk) {
                bf16x8 bw[4];
                #pragma unroll
                for (int n = 0; n < 4; ++n) {
                    const int row = n * 16 + l15;
                    bw[n] = *(const bf16x8*)(buf + row * WROWB +
                              ((s * 128 + kk * 64 + l4 * 16) ^ ((row & 7) << 4)));
                }
                #pragma unroll
                for (int m = 0; m < 4; ++m)
                    #pragma unroll
                    for (int n = 0; n < 4; ++n)
                        acc[m][n] = __builtin_amdgcn_mfma_f32_16x16x32_bf16(
                            af[kk][m], bw[n], acc[m][n], 0, 0, 0);
            }
        };

        bf16x8 afA[2][4], afB[2][4];
        issueA(0, afA); issueA(1, afB);
        SBAR(); SCHED();                               // window 0 ready
        for (int w = 0; w < NW; ++w) {
            const unsigned char* buf = lds + (w & 1) * WBUF;
            #pragma unroll
            for (int s = 0; s < 8; s += 2) {
                const int t = w * 8 + s;
                kstep(buf, s, afA);
                if (t + 2 < 64) issueA(t + 2, afA);
                kstep(buf, s + 1, afB);
                if (t + 3 < 64) issueA(t + 3, afB);
            }
            asm volatile("s_waitcnt lgkmcnt(0)" ::: "memory");
            SCHED(); SBAR(); SCHED();
        }

        // epilogue: C/D map col=lane&15, row=(lane>>4)*4+j
        #pragma unroll
        for (int n = 0; n < 4; ++n) {
            const int col = n0 + n * 16 + l15;
            const float bias = Bsrc[wn0 + n * 16 + l15];
            #pragma unroll
            for (int m = 0; m < 4; ++m) {
                const int row = wid * 64 + m * 16 + l4 * 4;
                f32x4 v = acc[m][n];
                #pragma unroll
                for (int j = 0; j < 4; ++j)
                    out[(size_t)(row + j) * ldout + col] = v[j] + bias;
            }
        }
    }
}

// gates z -> cell_new/hidden_new + bf16 plain-tiled hidden for gemm1
__global__ __launch_bounds__(256)
void lstm_elem(const float* __restrict__ z, const float* __restrict__ cell,
               float* __restrict__ cnew, float* __restrict__ hnew,
               unsigned char* __restrict__ A1)
{
    int id  = blockIdx.x * 256 + threadIdx.x;
    int row = id >> 9, col = (id & 511) * 8;
    const float* zr = z + (size_t)row * 16384 + col;
    f32x4 vf[2] = { *(const f32x4*)(zr),         *(const f32x4*)(zr + 4) };
    f32x4 vi[2] = { *(const f32x4*)(zr + 4096),  *(const f32x4*)(zr + 4100) };
    f32x4 vg[2] = { *(const f32x4*)(zr + 8192),  *(const f32x4*)(zr + 8196) };
    f32x4 vo[2] = { *(const f32x4*)(zr + 12288), *(const f32x4*)(zr + 12292) };
    const float* cr = cell + (size_t)row * 4096 + col;
    f32x4 vc[2] = { *(const f32x4*)cr, *(const f32x4*)(cr + 4) };
    f32x4 rc[2], rh[2];
    bf16x8 hb;
    #pragma unroll
    for (int h = 0; h < 2; ++h)
        #pragma unroll
        for (int j = 0; j < 4; ++j) {
            float f = 1.0f / (1.0f + __expf(-vf[h][j]));
            float i = 1.0f / (1.0f + __expf(-vi[h][j]));
            float g = tanhf(vg[h][j]);
            float o = 1.0f / (1.0f + __expf(-vo[h][j]));
            float cn = f * vc[h][j] + i * g;
            float hn = o * tanhf(cn);
            rc[h][j] = cn; rh[h][j] = hn;
            hb[h * 4 + j] = (__bf16)hn;
        }
    float* cd = cnew + (size_t)row * 4096 + col;
    float* hd = hnew + (size_t)row * 4096 + col;
    *(f32x4*)cd = rc[0]; *(f32x4*)(cd + 4) = rc[1];
    *(f32x4*)hd = rh[0]; *(f32x4*)(hd + 4) = rh[1];
    *(bf16x8*)(A1 + (size_t)(col >> 6) * ATILE + row * 128 + (col & 63) * 2) = hb;
}

__global__ __launch_bounds__(256)
void logsoftmax_inplace(float* __restrict__ out)
{
    float* row    = out + (size_t)blockIdx.x * 32000;
    const int tid = threadIdx.x;
    __shared__ float redm[4], reds[4];

    float m = -1e30f, s = 0.0f;
    for (int i = tid; i < 8000; i += 256) {
        f32x4 v = *(const f32x4*)(row + i * 4);
        float t = fmaxf(fmaxf(v[0], v[1]), fmaxf(v[2], v[3]));
        float nm = fmaxf(m, t);
        s = s * __expf(m - nm) + __expf(v[0] - nm) + __expf(v[1] - nm)
                               + __expf(v[2] - nm) + __expf(v[3] - nm);
        m = nm;
    }
    #pragma unroll
    for (int off = 32; off; off >>= 1) {
        float om = __shfl_xor(m, off), os = __shfl_xor(s, off);
        float nm = fmaxf(m, om);
        s = s * __expf(m - nm) + os * __expf(om - nm);
        m = nm;
    }
    if ((tid & 63) == 0) { redm[tid >> 6] = m; reds[tid >> 6] = s; }
    __syncthreads();
    {
        float M = fmaxf(fmaxf(redm[0], redm[1]), fmaxf(redm[2], redm[3]));
        float S = reds[0] * __expf(redm[0] - M) + reds[1] * __expf(redm[1] - M)
                + reds[2] * __expf(redm[2] - M) + reds[3] * __expf(redm[3] - M);
        m = M; s = S;
    }
    float lse = m + logf(s);

    for (int i = tid; i < 8000; i += 256) {
        f32x4 v = *(const f32x4*)(row + i * 4);
        v[0] -= lse; v[1] -= lse; v[2] -= lse; v[3] -= lse;
        *(f32x4*)(row + i * 4) = v;
    }
}

// Probe (owns the top-5): exact mirror of the producer DRAM pattern —
// 64-row panels, 2 KB contiguous per row per window, 8 windows, rep 8.
template <int REP>
__global__ __launch_bounds__(512)
void probe_w2k(const float* __restrict__ W, float* __restrict__ dump)
{
    const int tid = threadIdx.x, lane = tid & 63, wv = tid >> 6;
    const int r0 = wv * 8;
    f32x4 s[4] = {};
    for (int r = 0; r < REP; ++r) {
        const int n0 = (int)(((blockIdx.x + (unsigned)r * 211u) % 500u) * 64u);
        for (int w = 0; w < 8; ++w) {
            #pragma unroll
            for (int rr = 0; rr < 8; ++rr) {
                const float* p = W + (size_t)(n0 + r0 + rr) * 4096
                               + (size_t)w * 512 + lane * 8;
                s[rr & 3] += *(const f32x4*)p + *(const f32x4*)(p + 4);
            }
        }
    }
    f32x4 t = s[0] + s[1] + s[2] + s[3];
    dump[(size_t)blockIdx.x * 512 + tid] = t[0] + t[1] + t[2] + t[3];
}

extern "C" void kernel_launch(void* const* d_in, const int* in_sizes, int n_in,
                              void* d_out, int out_size, void* d_ws, size_t ws_size,
                              hipStream_t stream)
{
    const float* cat  = (const float*)d_in[0];
    const float* x    = (const float*)d_in[1];
    const float* hid  = (const float*)d_in[2];
    const float* cell = (const float*)d_in[3];
    const float* Wf   = (const float*)d_in[4];
    const float* bf   = (const float*)d_in[5];
    const float* Wi   = (const float*)d_in[6];
    const float* bi   = (const float*)d_in[7];
    const float* Wc   = (const float*)d_in[8];
    const float* bc   = (const float*)d_in[9];
    const float* Wo   = (const float*)d_in[10];
    const float* bo   = (const float*)d_in[11];
    const float* Wout = (const float*)d_in[12];
    const float* bout = (const float*)d_in[13];
    float* out = (float*)d_out;

    // ws: A0 (2MB) | A1 (2MB) | z (16MB) | dump @40MB
    unsigned char* A0 = (unsigned char*)d_ws;
    unsigned char* A1 = A0 + (size_t)64 * ATILE;
    float*         z  = (float*)(A1 + (size_t)64 * ATILE);
    float*       dump = (float*)((unsigned char*)d_ws + ((size_t)40 << 20));

    // d_out: [logits 256x32000 | cell_new 256x4096 | hidden_new 256x4096]
    float* cnew = out + 8192000;
    float* hnew = out + 9240576;

    prep_xc<<<512, 256, 0, stream>>>(cat, x, hid, A0);
    gemm_pc<0><<<256, 768, 0, stream>>>(A0, Wf, Wi, Wc, Wo, bf, bi, bc, bo, z, 16384);
    lstm_elem<<<512, 256, 0, stream>>>(z, cell, cnew, hnew, A1);
    gemm_pc<1><<<500, 768, 0, stream>>>(A1, Wout, nullptr, nullptr, nullptr,
                                        bout, nullptr, nullptr, nullptr, out, 32000);
    logsoftmax_inplace<<<256, 256, 0, stream>>>(out);

    // diagnostic: 2KB-visit W-stream pattern BW (4.2 GB; owns top-5 counters)
    probe_w2k<8><<<500, 512, 0, stream>>>(Wout, dump);
}

// Round 12
// 786.056 us; speedup vs baseline: 3.3306x; 1.4430x over previous
//
#include <hip/hip_runtime.h>
#include <cmath>

typedef __bf16 bf16x8 __attribute__((ext_vector_type(8)));
typedef float  f32x4  __attribute__((ext_vector_type(4)));

template <int N> struct IC { static constexpr int v = N; };

// GEMM: BM=256 (=M), BN=128, BK=64, 512 threads (8 waves).
#define ATILE 32768        // A tile: 256 rows * 128B (bf16, swizzled)
#define WTILE 16384        // W tile: 128 rows * 128B (bf16, swizzled)
#define LDS_W_OFF 65536    // after 2 A buffers

#define GLOAD_LDS16(g, l)                                                    \
    __builtin_amdgcn_global_load_lds(                                        \
        (const __attribute__((address_space(1))) unsigned int*)(g),          \
        (__attribute__((address_space(3))) unsigned int*)(l), 16, 0, 0)

#define SBAR()  __builtin_amdgcn_s_barrier()
#define SCHED() __builtin_amdgcn_sched_barrier(0)

__device__ __forceinline__ int swz(int row, int byteInRow) {
    return row * 128 + (byteInRow ^ ((row & 7) << 4));
}

__device__ __forceinline__ bf16x8 cvt8(f32x4 a, f32x4 b) {
    bf16x8 r;
    r[0] = (__bf16)a[0]; r[1] = (__bf16)a[1]; r[2] = (__bf16)a[2]; r[3] = (__bf16)a[3];
    r[4] = (__bf16)b[0]; r[5] = (__bf16)b[1]; r[6] = (__bf16)b[2]; r[7] = (__bf16)b[3];
    return r;
}

__global__ __launch_bounds__(256)
void prep_xc(const float* __restrict__ cat, const float* __restrict__ x,
             const float* __restrict__ hid, unsigned char* __restrict__ A0)
{
    int id  = blockIdx.x * 256 + threadIdx.x;
    int row = id >> 9, col = (id & 511) * 8;
    const float* src = (col < 512)  ? cat + (size_t)row * 512 + col
                     : (col < 2048) ? x   + (size_t)row * 1536 + (col - 512)
                                    : hid + (size_t)row * 2048 + (col - 2048);
    f32x4 a = *(const f32x4*)src, b = *(const f32x4*)(src + 4);
    int ks = col >> 6, c8 = (col & 63) >> 3;
    *(bf16x8*)(A0 + (size_t)ks * ATILE + swz(row, c8 * 16)) = cvt8(a, b);
}

// ===================== PRODUCTION GEMM (R4, frozen, 276us) =====================
template <int MODE>
__global__ __launch_bounds__(512, 2)
void gemm_bf16(const unsigned char* __restrict__ At,
               const float* __restrict__ W0, const float* __restrict__ W1,
               const float* __restrict__ W2, const float* __restrict__ W3,
               const float* __restrict__ B0, const float* __restrict__ B1,
               const float* __restrict__ B2, const float* __restrict__ B3,
               float* __restrict__ out, int ldout)
{
    __shared__ __align__(16) unsigned char lds[2 * ATILE + 2 * WTILE];

    constexpr int NKT = (MODE == 0) ? 32 : 64;

    const int tid  = threadIdx.x;
    const int lane = tid & 63;
    const int wid  = tid >> 6;
    const int l15  = lane & 15;
    const int l4   = lane >> 4;
    const int wr   = wid >> 1;
    const int wc   = wid & 1;

    int n0, koff; float* outp;
    if (MODE == 0) {
        n0 = (blockIdx.x >> 1) * 128;
        int kh = blockIdx.x & 1;
        koff = kh * 32;
        outp = out + (size_t)kh * 4194304;
    } else {
        n0 = blockIdx.x * 128; koff = 0; outp = out;
    }

    const float* Wsrc; const float* Bsrc; int wn0;
    if (MODE == 0) {
        int g = n0 >> 12;
        Wsrc = (g == 0) ? W0 : (g == 1) ? W1 : (g == 2) ? W2 : W3;
        Bsrc = (g == 0) ? B0 : (g == 1) ? B1 : (g == 2) ? B2 : B3;
        wn0  = n0 & 4095;
    } else {
        Wsrc = W0; Bsrc = B0; wn0 = n0;
    }

    f32x4 wreg[2][4];
    f32x4 acc[4][4] = {};

    const int wrow = tid >> 2;
    const int wkc  = tid & 3;
    const float* wbase = Wsrc + (size_t)(wn0 + wrow) * 4096 + (size_t)koff * 64 + wkc * 16;

    auto issueA = [&](int ks, int buf) {
        const unsigned char* src = At + (size_t)(koff + ks) * ATILE + wid * 4096 + lane * 16;
        unsigned char* dst = lds + buf * ATILE + wid * 4096;
        #pragma unroll
        for (int i = 0; i < 4; ++i)
            GLOAD_LDS16(src + i * 1024, dst + i * 1024);
    };
    auto loadW = [&](int ks, auto slot) {
        constexpr int S = decltype(slot)::v;
        const float* p = wbase + (size_t)ks * 64;
        wreg[S][0] = *(const f32x4*)p;
        wreg[S][1] = *(const f32x4*)(p + 4);
        wreg[S][2] = *(const f32x4*)(p + 8);
        wreg[S][3] = *(const f32x4*)(p + 12);
    };
    auto storeW = [&](auto slot, int buf) {
        constexpr int S = decltype(slot)::v;
        unsigned char* b = lds + LDS_W_OFF + buf * WTILE;
        *(bf16x8*)(b + swz(wrow, wkc * 32))      = cvt8(wreg[S][0], wreg[S][1]);
        *(bf16x8*)(b + swz(wrow, wkc * 32 + 16)) = cvt8(wreg[S][2], wreg[S][3]);
    };

    issueA(0, 0); loadW(0, IC<0>{});
    issueA(1, 1); loadW(1, IC<1>{});
    asm volatile("s_waitcnt vmcnt(8)" ::: "memory");
    SCHED();
    storeW(IC<0>{}, 0);
    asm volatile("s_waitcnt lgkmcnt(0)" ::: "memory");
    SBAR(); SCHED();

    auto step = [&](int t, auto curc) {
        constexpr int CUR = decltype(curc)::v;
        constexpr int OTH = CUR ^ 1;
        unsigned char* abase = lds + CUR * ATILE;
        unsigned char* wlds  = lds + LDS_W_OFF + CUR * WTILE;

        bf16x8 af[2][4], bw[2][4];
        #pragma unroll
        for (int kk = 0; kk < 2; ++kk) {
            #pragma unroll
            for (int m = 0; m < 4; ++m) {
                int row = wr * 64 + m * 16 + l15;
                af[kk][m] = *(const bf16x8*)(abase + swz(row, kk * 64 + l4 * 16));
            }
            #pragma unroll
            for (int n = 0; n < 4; ++n) {
                int row = wc * 64 + n * 16 + l15;
                bw[kk][n] = *(const bf16x8*)(wlds + swz(row, kk * 64 + l4 * 16));
            }
        }
        asm volatile("s_waitcnt lgkmcnt(0)" ::: "memory");
        SCHED(); SBAR(); SCHED();

        if (t + 2 < NKT) { issueA(t + 2, CUR); loadW(t + 2, curc); }
        #pragma unroll
        for (int kk = 0; kk < 2; ++kk)
            #pragma unroll
            for (int m = 0; m < 4; ++m)
                #pragma unroll
                for (int n = 0; n < 4; ++n)
                    acc[m][n] = __builtin_amdgcn_mfma_f32_16x16x32_bf16(
                        af[kk][m], bw[kk][n], acc[m][n], 0, 0, 0);
        if (t + 1 < NKT) {
            if (t + 2 < NKT) asm volatile("s_waitcnt vmcnt(8)" ::: "memory");
            else             asm volatile("s_waitcnt vmcnt(0)" ::: "memory");
            SCHED();
            storeW(IC<OTH>{}, OTH);
            asm volatile("s_waitcnt lgkmcnt(0)" ::: "memory");
        }
        SBAR(); SCHED();
    };

    for (int t = 0; t < NKT; t += 2) {
        step(t,     IC<0>{});
        step(t + 1, IC<1>{});
    }

    #pragma unroll
    for (int n = 0; n < 4; ++n) {
        int col = wc * 64 + n * 16 + l15;
        float bias = (MODE == 1 || koff == 0) ? Bsrc[wn0 + col] : 0.0f;
        #pragma unroll
        for (int m = 0; m < 4; ++m) {
            int row = wr * 64 + m * 16 + l4 * 4;
            f32x4 v = acc[m][n];
            #pragma unroll
            for (int j = 0; j < 4; ++j)
                outp[(size_t)(row + j) * ldout + n0 + col] = v[j] + bias;
        }
    }
}

__global__ __launch_bounds__(256)
void lstm_elem(const float* __restrict__ z0, const float* __restrict__ z1,
               const float* __restrict__ cell,
               float* __restrict__ cnew, float* __restrict__ hnew,
               unsigned char* __restrict__ A1)
{
    int id  = blockIdx.x * 256 + threadIdx.x;
    int row = id >> 9, col = (id & 511) * 8;
    const float* za = z0 + (size_t)row * 16384 + col;
    const float* zb = z1 + (size_t)row * 16384 + col;
    f32x4 vf[2], vi[2], vg[2], vo[2];
    #pragma unroll
    for (int h = 0; h < 2; ++h) {
        vf[h] = *(const f32x4*)(za + h * 4)         + *(const f32x4*)(zb + h * 4);
        vi[h] = *(const f32x4*)(za + 4096 + h * 4)  + *(const f32x4*)(zb + 4096 + h * 4);
        vg[h] = *(const f32x4*)(za + 8192 + h * 4)  + *(const f32x4*)(zb + 8192 + h * 4);
        vo[h] = *(const f32x4*)(za + 12288 + h * 4) + *(const f32x4*)(zb + 12288 + h * 4);
    }
    const float* cr = cell + (size_t)row * 4096 + col;
    f32x4 vc[2] = { *(const f32x4*)cr, *(const f32x4*)(cr + 4) };
    f32x4 rc[2], rh[2];
    bf16x8 hb;
    #pragma unroll
    for (int h = 0; h < 2; ++h)
        #pragma unroll
        for (int j = 0; j < 4; ++j) {
            float f = 1.0f / (1.0f + __expf(-vf[h][j]));
            float i = 1.0f / (1.0f + __expf(-vi[h][j]));
            float g = tanhf(vg[h][j]);
            float o = 1.0f / (1.0f + __expf(-vo[h][j]));
            float cn = f * vc[h][j] + i * g;
            float hn = o * tanhf(cn);
            rc[h][j] = cn; rh[h][j] = hn;
            hb[h * 4 + j] = (__bf16)hn;
        }
    float* cd = cnew + (size_t)row * 4096 + col;
    float* hd = hnew + (size_t)row * 4096 + col;
    *(f32x4*)cd = rc[0]; *(f32x4*)(cd + 4) = rc[1];
    *(f32x4*)hd = rh[0]; *(f32x4*)(hd + 4) = rh[1];
    int ks = col >> 6, c8 = (col & 63) >> 3;
    *(bf16x8*)(A1 + (size_t)ks * ATILE + swz(row, c8 * 16)) = hb;
}

__global__ __launch_bounds__(256)
void logsoftmax_inplace(float* __restrict__ out)
{
    float* row    = out + (size_t)blockIdx.x * 32000;
    const int tid = threadIdx.x;
    __shared__ float redm[4], reds[4];

    float m = -1e30f, s = 0.0f;
    for (int i = tid; i < 8000; i += 256) {
        f32x4 v = *(const f32x4*)(row + i * 4);
        float t = fmaxf(fmaxf(v[0], v[1]), fmaxf(v[2], v[3]));
        float nm = fmaxf(m, t);
        s = s * __expf(m - nm) + __expf(v[0] - nm) + __expf(v[1] - nm)
                               + __expf(v[2] - nm) + __expf(v[3] - nm);
        m = nm;
    }
    #pragma unroll
    for (int off = 32; off; off >>= 1) {
        float om = __shfl_xor(m, off), os = __shfl_xor(s, off);
        float nm = fmaxf(m, om);
        s = s * __expf(m - nm) + os * __expf(om - nm);
        m = nm;
    }
    if ((tid & 63) == 0) { redm[tid >> 6] = m; reds[tid >> 6] = s; }
    __syncthreads();
    {
        float M = fmaxf(fmaxf(redm[0], redm[1]), fmaxf(redm[2], redm[3]));
        float S = reds[0] * __expf(redm[0] - M) + reds[1] * __expf(redm[1] - M)
                + reds[2] * __expf(redm[2] - M) + reds[3] * __expf(redm[3] - M);
        m = M; s = S;
    }
    float lse = m + logf(s);

    for (int i = tid; i < 8000; i += 256) {
        f32x4 v = *(const f32x4*)(row + i * 4);
        v[0] -= lse; v[1] -= lse; v[2] -= lse; v[3] -= lse;
        *(f32x4*)(row + i * 4) = v;
    }
}

// ============== DISCRIMINATING PROBE: pure linear HBM read ==============
// 756 x 1MB chunks spanning ALL weights (792 MB >> 256 MB L3), rep=4 with
// panel hopping -> >= ~2.7 GB forced from HBM, perfectly coalesced
// (1 KB/wave bursts, contiguous 1 MB per block-chunk).
// Model A (CU-ingress cap 6.3): ~500us. Model B (HBM-read cap 3.2): ~900us.
template <int REP>
__global__ __launch_bounds__(256)
void probe_linear(const float* __restrict__ Wf, const float* __restrict__ Wi,
                  const float* __restrict__ Wc, const float* __restrict__ Wo,
                  const float* __restrict__ Wout, float* __restrict__ dump)
{
    const int tid = threadIdx.x;
    f32x4 s[4] = {};
    for (int r = 0; r < REP; ++r) {
        unsigned id = (blockIdx.x + (unsigned)r * 191u) % 756u;
        const float* base;
        if (id < 256u) {
            const float* m = (id < 64u) ? Wf : (id < 128u) ? Wi : (id < 192u) ? Wc : Wo;
            base = m + (size_t)(id & 63u) * 262144;
        } else {
            base = Wout + (size_t)(id - 256u) * 262144;
        }
        const f32x4* p = (const f32x4*)base + tid;
        #pragma unroll 4
        for (int i = 0; i < 256; ++i)
            s[i & 3] += p[i * 256];
    }
    f32x4 t = s[0] + s[1] + s[2] + s[3];
    dump[(size_t)blockIdx.x * 256 + tid] = t[0] + t[1] + t[2] + t[3];
}

extern "C" void kernel_launch(void* const* d_in, const int* in_sizes, int n_in,
                              void* d_out, int out_size, void* d_ws, size_t ws_size,
                              hipStream_t stream)
{
    const float* cat  = (const float*)d_in[0];
    const float* x    = (const float*)d_in[1];
    const float* hid  = (const float*)d_in[2];
    const float* cell = (const float*)d_in[3];
    const float* Wf   = (const float*)d_in[4];
    const float* bf   = (const float*)d_in[5];
    const float* Wi   = (const float*)d_in[6];
    const float* bi   = (const float*)d_in[7];
    const float* Wc   = (const float*)d_in[8];
    const float* bc   = (const float*)d_in[9];
    const float* Wo   = (const float*)d_in[10];
    const float* bo   = (const float*)d_in[11];
    const float* Wout = (const float*)d_in[12];
    const float* bout = (const float*)d_in[13];
    float* out = (float*)d_out;

    // ws: A0 (2MB) | A1 (2MB) | z0 (16MB) | z1 (16MB) | dump @40MB
    unsigned char* A0 = (unsigned char*)d_ws;
    unsigned char* A1 = A0 + (size_t)64 * ATILE;
    float*         z  = (float*)(A1 + (size_t)64 * ATILE);
    float*       dump = (float*)((unsigned char*)d_ws + ((size_t)40 << 20));

    // d_out: [logits 256x32000 | cell_new 256x4096 | hidden_new 256x4096]
    float* cnew = out + 8192000;
    float* hnew = out + 9240576;

    // -------- production (R4, frozen) --------
    prep_xc<<<512, 256, 0, stream>>>(cat, x, hid, A0);
    gemm_bf16<0><<<256, 512, 0, stream>>>(A0, Wf, Wi, Wc, Wo, bf, bi, bc, bo, z, 16384);
    lstm_elem<<<512, 256, 0, stream>>>(z, z + 4194304, cell, cnew, hnew, A1);
    gemm_bf16<1><<<250, 512, 0, stream>>>(A1, Wout, Wout, Wout, Wout,
                                          bout, bout, bout, bout, out, 32000);
    logsoftmax_inplace<<<256, 256, 0, stream>>>(out);

    // -------- discriminating probe: linear HBM read, all weights, rep 4 --------
    probe_linear<4><<<756, 256, 0, stream>>>(Wf, Wi, Wc, Wo, Wout, dump);
}